// Round 10
// baseline (280.506 us; speedup 1.0000x reference)
//
#include <hip/hip_runtime.h>

typedef unsigned int u32;

#define HW 3136
#define SCALE 0.08838834764831843f   // 128^-0.5

// workspace offsets (float units)
#define OFF_W7    0        // 128*49 combined dw weights (lepe BN folded)
#define OFF_BIAS  6272     // 128: lepe folded bias + fus_b
#define OFF_POOL  6400     // 4*128*49 pooled x_up
#define OFF_MT    31488    // 4*128*49, Mt[b][k][l]
#define OFF_D     56576    // 4*49
#define OFF_AVG   56772    // 4*128
#define OFF_MAXU  57284    // 4*128 (encoded u32)
#define OFF_WC    58308    // 128*128 fus_w @ wv
#define OFF_BC    74692    // 128 fus_w @ bv
#define OFF_WQKT  74820    // 128*128: WqkT[c][k] = sum_o wq[o,k]*wk[o,c]
#define OFF_DQ    91204    // 128
#define OFF_VB    91332    // 128
#define OFF_S0    91460    // 1 (+3 pad)
#define OFF_FV    91464    // 4*128*3136  fv = fus(value)
#define OFF_DYN   1697096  // 4*49*3136
#define OFF_XF    2311752  // 4*128*3136

struct Params {
  const float *x_up, *x_skip, *wq, *bq, *wk, *bk, *wv, *bv, *ww, *bw;
  const float *lk_w, *lk_s, *lk_b, *dw5, *s5, *b5, *dw3a, *s3a, *b3a,
              *dw3b, *s3b, *b3b, *dw3c, *s3c, *b3c, *lepe_s, *lepe_b;
  const float *gate_w, *gate_s, *gate_b, *fus_w, *fus_b, *ca_w1, *ca_w2, *res;
  float* W;
  float* out;
};

__device__ __forceinline__ u32 fenc(float f){
  union{float f; u32 u;} v; v.f = f;
  return (v.u & 0x80000000u) ? ~v.u : (v.u | 0x80000000u);
}
__device__ __forceinline__ float fdec(u32 u){
  union{float f; u32 uu;} v;
  v.uu = (u & 0x80000000u) ? (u ^ 0x80000000u) : ~u;
  return v.f;
}

// ---------------------------------------------------------------------------
// K0 (grid 642): [0,512) pooling per (b,c); [512,576) Wc; [576,640) WqkT;
// 640 W7/BIAS/init; 641 BC/DQ/VB/S0.
__global__ __launch_bounds__(256) void k_prep(Params P){
  __shared__ float pl[3136];
  __shared__ float part[208];
  float* W = P.W;
  const int tid = threadIdx.x, blk = blockIdx.x;
  if (blk < 512){
    const int b = blk >> 7, c = blk & 127;
    const float* src = P.x_up + (size_t)(b*128 + c)*HW;
    for (int idx = tid; idx < 784; idx += 256)
      *(float4*)&pl[idx*4] = *(const float4*)(src + idx*4);
    __syncthreads();
    if (tid < 196){
      const int l = tid >> 2, s = tid & 3;
      const int i = l/7, j = l%7;
      float sm = 0.f;
      #pragma unroll
      for (int r=0;r<2;++r){
        const int base = (8*i + 2*s + r)*56 + 8*j;
        #pragma unroll
        for (int e=0;e<8;++e) sm += pl[base+e];
      }
      part[tid] = sm;
    }
    __syncthreads();
    if (tid < 49){
      const float sm = part[tid*4] + part[tid*4+1] + part[tid*4+2] + part[tid*4+3];
      W[OFF_POOL + (size_t)(b*128+c)*49 + tid] = sm * (1.f/64.f);
    }
  } else if (blk < 576){
    const int o = (blk-512)*2 + (tid >> 7), c = tid & 127;
    float a = 0.f;
    #pragma unroll 8
    for (int m=0;m<128;++m) a += P.fus_w[o*128+m] * P.wv[m*128+c];
    W[OFF_WC + o*128 + c] = a;
  } else if (blk < 640){
    const int c = (blk-576)*2 + (tid >> 7), k = tid & 127;
    float a = 0.f;
    #pragma unroll 8
    for (int o=0;o<128;++o) a += P.wq[o*128+k] * P.wk[o*128+c];
    W[OFF_WQKT + c*128 + k] = a;
  } else if (blk == 640){
    for (int idx = tid; idx < 6272; idx += 256){
      const int c = idx/49, k = idx%49;
      const int dy = k/7 - 3, dx = k%7 - 3;
      float w = P.lk_s[c] * P.lk_w[c*49 + k];
      if (dy>=-2 && dy<=2 && dx>=-2 && dx<=2)
        w += P.s5[c] * P.dw5[c*25 + (dy+2)*5 + (dx+2)];
      if (dy>=-1 && dy<=1 && dx>=-1 && dx<=1)
        w += P.s3a[c] * P.dw3a[c*9 + (dy+1)*3 + (dx+1)];
      if ((dy==-2||dy==0||dy==2) && (dx==-2||dx==0||dx==2))
        w += P.s3b[c] * P.dw3b[c*9 + (dy/2+1)*3 + (dx/2+1)];
      if ((dy==-3||dy==0||dy==3) && (dx==-3||dx==0||dx==3))
        w += P.s3c[c] * P.dw3c[c*9 + (dy/3+1)*3 + (dx/3+1)];
      W[OFF_W7 + idx] = P.lepe_s[c] * w;
    }
    if (tid < 128){
      const float bs = P.lk_b[tid] + P.b5[tid] + P.b3a[tid] + P.b3b[tid] + P.b3c[tid];
      W[OFF_BIAS + tid] = P.lepe_s[tid] * bs + P.lepe_b[tid] + P.fus_b[tid];
    }
    for (int i = tid; i < 512; i += 256){
      W[OFF_AVG + i] = 0.f;
      ((u32*)W + OFF_MAXU)[i] = fenc(-1e30f);
    }
  } else {
    if (tid < 128){
      float bc = 0.f, dq = 0.f, vb = 0.f;
      #pragma unroll 8
      for (int m=0;m<128;++m){
        bc += P.fus_w[tid*128+m] * P.bv[m];
        dq += P.wq[m*128+tid] * P.bk[m];
        vb += P.bq[m] * P.wk[m*128+tid];
      }
      W[OFF_BC + tid] = bc;
      W[OFF_DQ + tid] = dq;
      W[OFF_VB + tid] = vb;
      if (tid == 0){
        float s = 0.f;
        for (int m=0;m<128;++m) s += P.bq[m]*P.bk[m];
        W[OFF_S0] = s;
      }
    }
  }
}

// ---------------------------------------------------------------------------
// K1 (196 x 128): Mt[b][k][l] = SCALE*(WqkT[:,k].pooled[:,l] + dq[k]);
// D[b][l] = SCALE*(vb . pooled[:,l] + s0).
__global__ __launch_bounds__(128) void k_mt(Params P){
  __shared__ float pc[128], red[128];
  float* W = P.W;
  const int b = blockIdx.x / 49, l = blockIdx.x % 49;
  const int t = threadIdx.x;
  pc[t] = W[OFF_POOL + (size_t)(b*128+t)*49 + l];
  __syncthreads();
  float acc = W[OFF_DQ + t];
  #pragma unroll 8
  for (int c=0;c<128;++c) acc += W[OFF_WQKT + c*128 + t] * pc[c];
  W[OFF_MT + (size_t)b*6272 + t*49 + l] = acc * SCALE;
  red[t] = W[OFF_VB + t] * pc[t];
  __syncthreads();
  if (t < 64) red[t] += red[t+64];
  __syncthreads();
  if (t < 32) red[t] += red[t+32];
  __syncthreads();
  if (t < 16) red[t] += red[t+16];
  __syncthreads();
  if (t < 8) red[t] += red[t+8];
  __syncthreads();
  if (t < 4) red[t] += red[t+4];
  __syncthreads();
  if (t == 0)
    W[OFF_D + b*49 + l] = (red[0]+red[1]+red[2]+red[3] + W[OFF_S0]) * SCALE;
}

// ---------------------------------------------------------------------------
// K2 (grid 784): fused fv-GEMM + attention + dyn. One x_skip strip stage.
// Phase A: fv = Wc@x + bc (LDS-staged weights, union buffer sh).
// Phase B: logits = x^T Mt + D (Mt staged into sh), softmax, dyn = ww@attn+bw.
__global__ __launch_bounds__(256) void k_qvattn(Params P){
  __shared__ float xl[128][20];
  __shared__ float sh[6272];       // Phase A: wl[32][133] (4256); Phase B: Mt
  __shared__ float wwl[2401];
  __shared__ float attl[16][52];
  __shared__ float dvl[52];
  float* W = P.W;
  const int tid = threadIdx.x;
  const int x = blockIdx.x, xcd = x & 7;
  const int b = xcd >> 1;
  const int p0 = ((xcd & 1) + 2*(x >> 3)) * 16;

  for (int idx = tid; idx < 512; idx += 256){
    const int c = idx >> 2, pq = idx & 3;
    *(float4*)&xl[c][pq*4] =
        *(const float4*)(P.x_skip + (size_t)(b*128+c)*HW + p0 + pq*4);
  }
  // staging for phase B that doesn't conflict with phase A:
  for (int idx = tid; idx < 600; idx += 256)
    *(float4*)&wwl[idx*4] = *(const float4*)(P.ww + idx*4);
  if (tid == 0) wwl[2400] = P.ww[2400];
  if (tid < 49) dvl[tid] = W[OFF_D + b*49 + tid];

  // ---- Phase A: fv GEMM
  const int oq = tid >> 2, pq = tid & 3;
  const int o0 = oq*2, pxa = pq*4;
  const float i0 = W[OFF_BC + o0], i1 = W[OFF_BC + o0 + 1];
  float a0[4], a1[4];
  #pragma unroll
  for (int j=0;j<4;++j){ a0[j]=i0; a1[j]=i1; }
  for (int g=0; g<4; ++g){
    __syncthreads();
    for (int idx = tid; idx < 1024; idx += 256){
      const int o = idx >> 3, kq = idx & 7;
      const float4 v = *(const float4*)(W + OFF_WC + (size_t)o*128 + g*32 + kq*4);
      sh[(kq*4+0)*133+o] = v.x; sh[(kq*4+1)*133+o] = v.y;
      sh[(kq*4+2)*133+o] = v.z; sh[(kq*4+3)*133+o] = v.w;
    }
    __syncthreads();
    #pragma unroll 8
    for (int k=0;k<32;++k){
      const float2 w2 = *(const float2*)&sh[k*133+o0];
      const float4 x4 = *(const float4*)&xl[g*32+k][pxa];
      const float xv[4] = {x4.x,x4.y,x4.z,x4.w};
      #pragma unroll
      for (int j=0;j<4;++j){ a0[j] += w2.x*xv[j]; a1[j] += w2.y*xv[j]; }
    }
  }
  {
    float4 v0 = {a0[0],a0[1],a0[2],a0[3]};
    float4 v1 = {a1[0],a1[1],a1[2],a1[3]};
    *(float4*)(W + OFF_FV + (size_t)(b*128+o0  )*HW + p0 + pxa) = v0;
    *(float4*)(W + OFF_FV + (size_t)(b*128+o0+1)*HW + p0 + pxa) = v1;
  }

  // ---- Phase B: attention
  __syncthreads();   // all reads of sh-as-wl done
  for (int idx = tid; idx < 1568; idx += 256)
    *(float4*)&sh[idx*4] = *(const float4*)(W + OFF_MT + (size_t)b*6272 + idx*4);
  __syncthreads();

  const int px = tid >> 4, sub = tid & 15;
  const int l0 = sub, l1 = sub+16, l2 = sub+32, l3 = sub+48;
  const int l3c = (l3 < 49) ? l3 : 48;
  float lv0 = dvl[l0], lv1 = dvl[l1], lv2 = dvl[l2];
  float lv3 = (l3 < 49) ? dvl[l3] : -1e30f;
  float a3 = 0.f;
  #pragma unroll 4
  for (int c=0;c<128;++c){
    const float xv = xl[c][px];
    lv0 += sh[c*49+l0]*xv;
    lv1 += sh[c*49+l1]*xv;
    lv2 += sh[c*49+l2]*xv;
    a3  += sh[c*49+l3c]*xv;
  }
  if (l3 < 49) lv3 += a3;

  float m = fmaxf(fmaxf(lv0, lv1), fmaxf(lv2, lv3));
  #pragma unroll
  for (int d=1; d<16; d<<=1) m = fmaxf(m, __shfl_xor(m, d, 64));
  const float e0 = __expf(lv0-m), e1 = __expf(lv1-m), e2 = __expf(lv2-m);
  const float e3 = (l3 < 49) ? __expf(lv3-m) : 0.f;
  float s = e0+e1+e2+e3;
  #pragma unroll
  for (int d=1; d<16; d<<=1) s += __shfl_xor(s, d, 64);
  const float inv = 1.f / s;
  attl[px][l0] = e0*inv;
  attl[px][l1] = e1*inv;
  attl[px][l2] = e2*inv;
  if (l3 < 49) attl[px][l3] = e3*inv;
  __syncthreads();

  #pragma unroll
  for (int j=0;j<4;++j){
    const int oo = sub + 16*j;
    if (oo < 49){
      float a = P.bw[oo];
      #pragma unroll 7
      for (int l=0;l<49;++l) a += wwl[oo*49+l] * attl[px][l];
      W[OFF_DYN + (size_t)(b*49+oo)*HW + p0 + px] = a;
    }
  }
}

// ---------------------------------------------------------------------------
// K3 (grid 1024): fused dyn-7x7 on fv + lepe-7x7 on x_skip + bias + CA partials.
__global__ __launch_bounds__(256) void k_mix(Params P){
  __shared__ float fvs[2][20][64];
  __shared__ float xss[2][20][64];
  __shared__ float w7s[2][49];
  float* W = P.W;
  const int tid = threadIdx.x;
  const int blk = blockIdx.x, xcd = blk & 7;
  const int b = xcd >> 1;
  const int idx2 = blk >> 3;
  const int cp = idx2 >> 1;
  const int qt = (xcd & 1) + 2*(idx2 & 1);
  const int c0 = cp*2, r0 = qt*14;

  for (int idx = tid; idx < 1280; idx += 256){
    const int a2 = idx / 320;
    const int ch = a2 & 1, arr = a2 >> 1;
    const int rem = idx % 320;
    const int rr = rem >> 4, cq = rem & 15;
    const int gr = r0 - 3 + rr, gc0 = cq*4 - 4;
    float4 v = {0.f,0.f,0.f,0.f};
    if ((unsigned)gr < 56u){
      const float* src = arr ? (P.x_skip + (size_t)(b*128 + c0 + ch)*HW + gr*56)
                             : (W + OFF_FV + (size_t)(b*128 + c0 + ch)*HW + gr*56);
      if (gc0 >= 0 && gc0 + 3 < 56){
        v = *(const float4*)(src + gc0);
      } else {
        float t[4];
        #pragma unroll
        for (int e=0;e<4;++e){
          const int gc = gc0 + e;
          t[e] = ((unsigned)gc < 56u) ? src[gc] : 0.f;
        }
        v.x=t[0]; v.y=t[1]; v.z=t[2]; v.w=t[3];
      }
    }
    if (arr) *(float4*)&xss[ch][rr][cq*4] = v;
    else     *(float4*)&fvs[ch][rr][cq*4] = v;
  }
  if (tid < 98) w7s[tid/49][tid%49] = W[OFF_W7 + (c0 + tid/49)*49 + tid%49];
  __syncthreads();

  const bool act = tid < 196;
  const int row = tid / 14, q = tid % 14;
  const int q4 = q*4;
  const int grow = r0 + row;
  float acc[2][4];
  {
    const float b0 = W[OFF_BIAS + c0], b1 = W[OFF_BIAS + c0 + 1];
    #pragma unroll
    for (int e=0;e<4;++e){ acc[0][e] = b0; acc[1][e] = b1; }
  }
  if (act){
    const float* dynb = W + OFF_DYN + (size_t)b*49*HW + grow*56 + q4;
    #pragma unroll
    for (int i=0;i<7;++i){
      float4 dr[7];
      #pragma unroll
      for (int j=0;j<7;++j)
        dr[j] = *(const float4*)(dynb + (size_t)(i*7+j)*HW);
      #pragma unroll
      for (int ch=0;ch<2;++ch){
        float fw[12], xw[12];
        {
          float4 t;
          t = *(const float4*)&fvs[ch][row+i][q4];    fw[0]=t.x;fw[1]=t.y;fw[2]=t.z;fw[3]=t.w;
          t = *(const float4*)&fvs[ch][row+i][q4+4];  fw[4]=t.x;fw[5]=t.y;fw[6]=t.z;fw[7]=t.w;
          t = *(const float4*)&fvs[ch][row+i][q4+8];  fw[8]=t.x;fw[9]=t.y;fw[10]=t.z;fw[11]=t.w;
          t = *(const float4*)&xss[ch][row+i][q4];    xw[0]=t.x;xw[1]=t.y;xw[2]=t.z;xw[3]=t.w;
          t = *(const float4*)&xss[ch][row+i][q4+4];  xw[4]=t.x;xw[5]=t.y;xw[6]=t.z;xw[7]=t.w;
          t = *(const float4*)&xss[ch][row+i][q4+8];  xw[8]=t.x;xw[9]=t.y;xw[10]=t.z;xw[11]=t.w;
        }
        #pragma unroll
        for (int j=0;j<7;++j){
          const float4 dv = dr[j];
          const float wv = w7s[ch][i*7+j];
          acc[ch][0] += dv.x*fw[j+1] + wv*xw[j+1];
          acc[ch][1] += dv.y*fw[j+2] + wv*xw[j+2];
          acc[ch][2] += dv.z*fw[j+3] + wv*xw[j+3];
          acc[ch][3] += dv.w*fw[j+4] + wv*xw[j+4];
        }
      }
    }
    #pragma unroll
    for (int ch=0;ch<2;++ch){
      float4 v = {acc[ch][0], acc[ch][1], acc[ch][2], acc[ch][3]};
      *(float4*)(W + OFF_XF + (size_t)(b*128 + c0 + ch)*HW + grow*56 + q4) = v;
    }
  }
  #pragma unroll
  for (int ch=0;ch<2;++ch){
    float s = act ? (acc[ch][0]+acc[ch][1]+acc[ch][2]+acc[ch][3]) : 0.f;
    float mm = act ? fmaxf(fmaxf(acc[ch][0],acc[ch][1]),
                           fmaxf(acc[ch][2],acc[ch][3])) : -1e30f;
    #pragma unroll
    for (int d=1; d<64; d<<=1){
      s += __shfl_xor(s, d, 64);
      mm = fmaxf(mm, __shfl_xor(mm, d, 64));
    }
    if ((tid & 63) == 0){
      atomicAdd(W + OFF_AVG + b*128 + c0 + ch, s);
      atomicMax((u32*)W + OFF_MAXU + b*128 + c0 + ch, fenc(mm));
    }
  }
}

// ---------------------------------------------------------------------------
// K4 (grid 784): CA MLP (recomputed per block) + gate-GEMM + epilogue.
__global__ __launch_bounds__(256) void k_final(Params P){
  __shared__ float xl[128][20];
  __shared__ float wl[32][133];
  __shared__ float hl[16], cal[128];
  float* W = P.W;
  const int tid = threadIdx.x;
  const int x = blockIdx.x, xcd = x & 7;
  const int b = xcd >> 1;
  const int p0 = ((xcd & 1) + 2*(x >> 3)) * 16;

  for (int idx = tid; idx < 512; idx += 256){
    const int c = idx >> 2, pq = idx & 3;
    *(float4*)&xl[c][pq*4] =
        *(const float4*)(P.x_skip + (size_t)(b*128+c)*HW + p0 + pq*4);
  }
  // CA MLP phase 1: h[r] for avg (r<8) and max (r>=8)
  if (tid < 16){
    const int r = tid & 7, which = tid >> 3;
    float a = 0.f;
    #pragma unroll 8
    for (int c=0;c<128;++c){
      const float v = which ? fdec(((u32*)W + OFF_MAXU)[b*128+c])
                            : W[OFF_AVG + b*128+c] * (1.f/3136.f);
      a += P.ca_w1[r*128+c] * v;
    }
    hl[tid] = fmaxf(a, 0.f);
  }
  __syncthreads();
  if (tid < 128){
    float a = 0.f;
    #pragma unroll
    for (int r=0;r<8;++r) a += P.ca_w2[tid*8+r] * (hl[r] + hl[8+r]);
    cal[tid] = 1.f/(1.f + __expf(-a));
  }

  const int oq = tid >> 2, pq = tid & 3;
  const int o0 = oq*2, px = pq*4;
  float a0[4] = {0.f,0.f,0.f,0.f}, a1[4] = {0.f,0.f,0.f,0.f};

  for (int g=0; g<4; ++g){
    __syncthreads();
    for (int idx = tid; idx < 1024; idx += 256){
      const int o = idx >> 3, kq = idx & 7;
      const float4 v = *(const float4*)(P.gate_w + (size_t)o*128 + g*32 + kq*4);
      wl[kq*4+0][o] = v.x; wl[kq*4+1][o] = v.y;
      wl[kq*4+2][o] = v.z; wl[kq*4+3][o] = v.w;
    }
    __syncthreads();
    #pragma unroll 8
    for (int k=0;k<32;++k){
      const float2 w2 = *(const float2*)&wl[k][o0];
      const float4 x4 = *(const float4*)&xl[g*32+k][px];
      const float xv[4] = {x4.x,x4.y,x4.z,x4.w};
      #pragma unroll
      for (int j=0;j<4;++j){ a0[j] += w2.x*xv[j]; a1[j] += w2.y*xv[j]; }
    }
  }
  const float s0 = P.gate_s[o0], s1 = P.gate_s[o0+1];
  const float c0 = P.gate_b[o0], c1 = P.gate_b[o0+1];
  const float ca0 = cal[o0], ca1 = cal[o0+1];
  const float res = P.res[0];
  const float4 xf0 = *(const float4*)(W + OFF_XF + (size_t)(b*128+o0  )*HW + p0 + px);
  const float4 xf1 = *(const float4*)(W + OFF_XF + (size_t)(b*128+o0+1)*HW + p0 + px);
  const float4 sk0 = *(const float4*)&xl[o0][px];
  const float4 sk1 = *(const float4*)&xl[o0+1][px];
  float g0[4] = {a0[0],a0[1],a0[2],a0[3]};
  float g1[4] = {a1[0],a1[1],a1[2],a1[3]};
  #pragma unroll
  for (int j=0;j<4;++j){
    float y0 = s0*g0[j] + c0, y1 = s1*g1[j] + c1;
    g0[j] = y0 / (1.f + __expf(-y0));
    g1[j] = y1 / (1.f + __expf(-y1));
  }
  float4 o0v, o1v;
  o0v.x = g0[0]*ca0*xf0.x + sk0.x*res;
  o0v.y = g0[1]*ca0*xf0.y + sk0.y*res;
  o0v.z = g0[2]*ca0*xf0.z + sk0.z*res;
  o0v.w = g0[3]*ca0*xf0.w + sk0.w*res;
  o1v.x = g1[0]*ca1*xf1.x + sk1.x*res;
  o1v.y = g1[1]*ca1*xf1.y + sk1.y*res;
  o1v.z = g1[2]*ca1*xf1.z + sk1.z*res;
  o1v.w = g1[3]*ca1*xf1.w + sk1.w*res;
  *(float4*)(P.out + (size_t)(b*128+o0  )*HW + p0 + px) = o0v;
  *(float4*)(P.out + (size_t)(b*128+o0+1)*HW + p0 + px) = o1v;
}

// ---------------------------------------------------------------------------
extern "C" void kernel_launch(void* const* d_in, const int* in_sizes, int n_in,
                              void* d_out, int out_size, void* d_ws, size_t ws_size,
                              hipStream_t stream){
  Params P;
  const float* const* in = (const float* const*)d_in;
  P.x_up = in[0];  P.x_skip = in[1]; P.wq = in[2];  P.bq = in[3];
  P.wk = in[4];    P.bk = in[5];     P.wv = in[6];  P.bv = in[7];
  P.ww = in[8];    P.bw = in[9];
  P.lk_w = in[10]; P.lk_s = in[11];  P.lk_b = in[12];
  P.dw5 = in[13];  P.s5 = in[14];    P.b5 = in[15];
  P.dw3a = in[16]; P.s3a = in[17];   P.b3a = in[18];
  P.dw3b = in[19]; P.s3b = in[20];   P.b3b = in[21];
  P.dw3c = in[22]; P.s3c = in[23];   P.b3c = in[24];
  P.lepe_s = in[25]; P.lepe_b = in[26];
  P.gate_w = in[27]; P.gate_s = in[28]; P.gate_b = in[29];
  P.fus_w = in[30];  P.fus_b = in[31];
  P.ca_w1 = in[32];  P.ca_w2 = in[33]; P.res = in[34];
  P.W = (float*)d_ws;
  P.out = (float*)d_out;

  hipLaunchKernelGGL(k_prep,   dim3(642), dim3(256), 0, stream, P);
  hipLaunchKernelGGL(k_mt,     dim3(196), dim3(128), 0, stream, P);
  hipLaunchKernelGGL(k_qvattn, dim3(784), dim3(256), 0, stream, P);
  hipLaunchKernelGGL(k_mix,    dim3(1024),dim3(256), 0, stream, P);
  hipLaunchKernelGGL(k_final,  dim3(784), dim3(256), 0, stream, P);
}

// Round 11
// 265.993 us; speedup vs baseline: 1.0546x; 1.0546x over previous
//
#include <hip/hip_runtime.h>

typedef unsigned int u32;

#define HW 3136
#define SCALE 0.08838834764831843f   // 128^-0.5

// workspace offsets (float units)
#define OFF_W7    0
#define OFF_BIAS  6272
#define OFF_POOL  6400
#define OFF_MT    31488
#define OFF_D     56576
#define OFF_AVG   56772
#define OFF_MAXU  57284
#define OFF_WC    58308
#define OFF_BC    74692
#define OFF_WQKT  74820
#define OFF_DQ    91204
#define OFF_VB    91332
#define OFF_S0    91460
#define OFF_FV    91464
#define OFF_DYN   1697096
#define OFF_XF    2311752

struct Params {
  const float *x_up, *x_skip, *wq, *bq, *wk, *bk, *wv, *bv, *ww, *bw;
  const float *lk_w, *lk_s, *lk_b, *dw5, *s5, *b5, *dw3a, *s3a, *b3a,
              *dw3b, *s3b, *b3b, *dw3c, *s3c, *b3c, *lepe_s, *lepe_b;
  const float *gate_w, *gate_s, *gate_b, *fus_w, *fus_b, *ca_w1, *ca_w2, *res;
  float* W;
  float* out;
};

__device__ __forceinline__ u32 fenc(float f){
  union{float f; u32 u;} v; v.f = f;
  return (v.u & 0x80000000u) ? ~v.u : (v.u | 0x80000000u);
}
__device__ __forceinline__ float fdec(u32 u){
  union{float f; u32 uu;} v;
  v.uu = (u & 0x80000000u) ? (u ^ 0x80000000u) : ~u;
  return v.f;
}

// ---------------------------------------------------------------------------
// K0 (grid 642): [0,512) pooling per (b,c); [512,576) Wc; [576,640) WqkT;
// 640 W7/BIAS/init; 641 BC/DQ/VB/S0.
__global__ __launch_bounds__(256) void k_prep(Params P){
  __shared__ float pl[3136];
  __shared__ float part[208];
  float* W = P.W;
  const int tid = threadIdx.x, blk = blockIdx.x;
  if (blk < 512){
    const int b = blk >> 7, c = blk & 127;
    const float* src = P.x_up + (size_t)(b*128 + c)*HW;
    for (int idx = tid; idx < 784; idx += 256)
      *(float4*)&pl[idx*4] = *(const float4*)(src + idx*4);
    __syncthreads();
    if (tid < 196){
      const int l = tid >> 2, s = tid & 3;
      const int i = l/7, j = l%7;
      float sm = 0.f;
      #pragma unroll
      for (int r=0;r<2;++r){
        const int base = (8*i + 2*s + r)*56 + 8*j;
        #pragma unroll
        for (int e=0;e<8;++e) sm += pl[base+e];
      }
      part[tid] = sm;
    }
    __syncthreads();
    if (tid < 49){
      const float sm = part[tid*4] + part[tid*4+1] + part[tid*4+2] + part[tid*4+3];
      W[OFF_POOL + (size_t)(b*128+c)*49 + tid] = sm * (1.f/64.f);
    }
  } else if (blk < 576){
    const int o = (blk-512)*2 + (tid >> 7), c = tid & 127;
    float a = 0.f;
    #pragma unroll 8
    for (int m=0;m<128;++m) a += P.fus_w[o*128+m] * P.wv[m*128+c];
    W[OFF_WC + o*128 + c] = a;
  } else if (blk < 640){
    const int c = (blk-576)*2 + (tid >> 7), k = tid & 127;
    float a = 0.f;
    #pragma unroll 8
    for (int o=0;o<128;++o) a += P.wq[o*128+k] * P.wk[o*128+c];
    W[OFF_WQKT + c*128 + k] = a;
  } else if (blk == 640){
    for (int idx = tid; idx < 6272; idx += 256){
      const int c = idx/49, k = idx%49;
      const int dy = k/7 - 3, dx = k%7 - 3;
      float w = P.lk_s[c] * P.lk_w[c*49 + k];
      if (dy>=-2 && dy<=2 && dx>=-2 && dx<=2)
        w += P.s5[c] * P.dw5[c*25 + (dy+2)*5 + (dx+2)];
      if (dy>=-1 && dy<=1 && dx>=-1 && dx<=1)
        w += P.s3a[c] * P.dw3a[c*9 + (dy+1)*3 + (dx+1)];
      if ((dy==-2||dy==0||dy==2) && (dx==-2||dx==0||dx==2))
        w += P.s3b[c] * P.dw3b[c*9 + (dy/2+1)*3 + (dx/2+1)];
      if ((dy==-3||dy==0||dy==3) && (dx==-3||dx==0||dx==3))
        w += P.s3c[c] * P.dw3c[c*9 + (dy/3+1)*3 + (dx/3+1)];
      W[OFF_W7 + idx] = P.lepe_s[c] * w;
    }
    if (tid < 128){
      const float bs = P.lk_b[tid] + P.b5[tid] + P.b3a[tid] + P.b3b[tid] + P.b3c[tid];
      W[OFF_BIAS + tid] = P.lepe_s[tid] * bs + P.lepe_b[tid] + P.fus_b[tid];
    }
    for (int i = tid; i < 512; i += 256){
      W[OFF_AVG + i] = 0.f;
      ((u32*)W + OFF_MAXU)[i] = fenc(-1e30f);
    }
  } else {
    if (tid < 128){
      float bc = 0.f, dq = 0.f, vb = 0.f;
      #pragma unroll 8
      for (int m=0;m<128;++m){
        bc += P.fus_w[tid*128+m] * P.bv[m];
        dq += P.wq[m*128+tid] * P.bk[m];
        vb += P.bq[m] * P.wk[m*128+tid];
      }
      W[OFF_BC + tid] = bc;
      W[OFF_DQ + tid] = dq;
      W[OFF_VB + tid] = vb;
      if (tid == 0){
        float s = 0.f;
        for (int m=0;m<128;++m) s += P.bq[m]*P.bk[m];
        W[OFF_S0] = s;
      }
    }
  }
}

// ---------------------------------------------------------------------------
// K1 (196 x 256): Mt[b][k][l] split-c over 2 thread halves; D via wave shuffle.
__global__ __launch_bounds__(256) void k_mt(Params P){
  __shared__ float pc[128];
  __shared__ float part[256];
  float* W = P.W;
  const int b = blockIdx.x / 49, l = blockIdx.x % 49;
  const int tid = threadIdx.x;
  if (tid < 128) pc[tid] = W[OFF_POOL + (size_t)(b*128+tid)*49 + l];
  __syncthreads();
  const int t = tid & 127, h = tid >> 7;
  const int c0 = h*64;
  float acc = h ? 0.f : W[OFF_DQ + t];
  #pragma unroll 8
  for (int c=0;c<64;++c) acc += W[OFF_WQKT + (size_t)(c0+c)*128 + t] * pc[c0+c];
  part[tid] = acc;
  __syncthreads();
  if (tid < 128)
    W[OFF_MT + (size_t)b*6272 + tid*49 + l] = (part[tid] + part[tid+128]) * SCALE;
  else if (tid < 192){
    const int u = tid - 128;   // 0..63
    float r = W[OFF_VB + u]*pc[u] + W[OFF_VB + u+64]*pc[u+64];
    #pragma unroll
    for (int d=1; d<64; d<<=1) r += __shfl_xor(r, d, 64);
    if (u == 0) W[OFF_D + b*49 + l] = (r + W[OFF_S0]) * SCALE;
  }
}

// ---------------------------------------------------------------------------
// K2 (grid 784): fused fv-GEMM (register-streamed Wc) + attention + dyn.
// 2 barriers total.
__global__ __launch_bounds__(256) void k_qvattn(Params P){
  __shared__ float xl[128][20];
  __shared__ float sh[6272];       // Mt[b] linear
  __shared__ float wwl[2401];
  __shared__ float attl[16][52];
  __shared__ float dvl[52];
  float* W = P.W;
  const int tid = threadIdx.x;
  const int x = blockIdx.x, xcd = x & 7;
  const int b = xcd >> 1;
  const int p0 = ((xcd & 1) + 2*(x >> 3)) * 16;

  for (int idx = tid; idx < 512; idx += 256){
    const int c = idx >> 2, pq = idx & 3;
    *(float4*)&xl[c][pq*4] =
        *(const float4*)(P.x_skip + (size_t)(b*128+c)*HW + p0 + pq*4);
  }
  for (int idx = tid; idx < 1568; idx += 256)
    *(float4*)&sh[idx*4] = *(const float4*)(W + OFF_MT + (size_t)b*6272 + idx*4);
  for (int idx = tid; idx < 600; idx += 256)
    *(float4*)&wwl[idx*4] = *(const float4*)(P.ww + idx*4);
  if (tid == 0) wwl[2400] = P.ww[2400];
  if (tid < 49) dvl[tid] = W[OFF_D + b*49 + tid];
  __syncthreads();                                   // barrier 1

  // ---- Phase A: fv GEMM, weights streamed from L2 (rows o0, o0+1)
  const int oq = tid >> 2, pq = tid & 3;
  const int o0 = oq*2, pxa = pq*4;
  const float4* __restrict__ wr0 = (const float4*)(W + OFF_WC + (size_t)o0*128);
  const float4* __restrict__ wr1 = (const float4*)(W + OFF_WC + (size_t)(o0+1)*128);
  const float i0 = W[OFF_BC + o0], i1 = W[OFF_BC + o0 + 1];
  float a0[4], a1[4];
  #pragma unroll
  for (int j=0;j<4;++j){ a0[j]=i0; a1[j]=i1; }
  #pragma unroll 4
  for (int g=0; g<32; ++g){
    const float4 wa = wr0[g], wb = wr1[g];
    const float wav[4] = {wa.x,wa.y,wa.z,wa.w};
    const float wbv[4] = {wb.x,wb.y,wb.z,wb.w};
    #pragma unroll
    for (int t=0; t<4; ++t){
      const float4 x4 = *(const float4*)&xl[g*4+t][pxa];
      a0[0] += wav[t]*x4.x; a0[1] += wav[t]*x4.y;
      a0[2] += wav[t]*x4.z; a0[3] += wav[t]*x4.w;
      a1[0] += wbv[t]*x4.x; a1[1] += wbv[t]*x4.y;
      a1[2] += wbv[t]*x4.z; a1[3] += wbv[t]*x4.w;
    }
  }
  {
    float4 v0 = {a0[0],a0[1],a0[2],a0[3]};
    float4 v1 = {a1[0],a1[1],a1[2],a1[3]};
    *(float4*)(W + OFF_FV + (size_t)(b*128+o0  )*HW + p0 + pxa) = v0;
    *(float4*)(W + OFF_FV + (size_t)(b*128+o0+1)*HW + p0 + pxa) = v1;
  }

  // ---- Phase B: attention (Mt already in sh)
  const int px = tid >> 4, sub = tid & 15;
  const int l0 = sub, l1 = sub+16, l2 = sub+32, l3 = sub+48;
  const int l3c = (l3 < 49) ? l3 : 48;
  float lv0 = dvl[l0], lv1 = dvl[l1], lv2 = dvl[l2];
  float lv3 = (l3 < 49) ? dvl[l3] : -1e30f;
  float a3 = 0.f;
  #pragma unroll 4
  for (int c=0;c<128;++c){
    const float xv = xl[c][px];
    lv0 += sh[c*49+l0]*xv;
    lv1 += sh[c*49+l1]*xv;
    lv2 += sh[c*49+l2]*xv;
    a3  += sh[c*49+l3c]*xv;
  }
  if (l3 < 49) lv3 += a3;

  float m = fmaxf(fmaxf(lv0, lv1), fmaxf(lv2, lv3));
  #pragma unroll
  for (int d=1; d<16; d<<=1) m = fmaxf(m, __shfl_xor(m, d, 64));
  const float e0 = __expf(lv0-m), e1 = __expf(lv1-m), e2 = __expf(lv2-m);
  const float e3 = (l3 < 49) ? __expf(lv3-m) : 0.f;
  float s = e0+e1+e2+e3;
  #pragma unroll
  for (int d=1; d<16; d<<=1) s += __shfl_xor(s, d, 64);
  const float inv = 1.f / s;
  attl[px][l0] = e0*inv;
  attl[px][l1] = e1*inv;
  attl[px][l2] = e2*inv;
  if (l3 < 49) attl[px][l3] = e3*inv;
  __syncthreads();                                   // barrier 2

  #pragma unroll
  for (int j=0;j<4;++j){
    const int oo = sub + 16*j;
    if (oo < 49){
      float a = P.bw[oo];
      #pragma unroll 7
      for (int l=0;l<49;++l) a += wwl[oo*49+l] * attl[px][l];
      W[OFF_DYN + (size_t)(b*49+oo)*HW + p0 + px] = a;
    }
  }
}

// ---------------------------------------------------------------------------
// K3 (grid 1024): fused dyn-7x7 on fv + lepe-7x7 on x_skip + bias + CA partials.
__global__ __launch_bounds__(256) void k_mix(Params P){
  __shared__ float fvs[2][20][64];
  __shared__ float xss[2][20][64];
  __shared__ float w7s[2][49];
  float* W = P.W;
  const int tid = threadIdx.x;
  const int blk = blockIdx.x, xcd = blk & 7;
  const int b = xcd >> 1;
  const int idx2 = blk >> 3;
  const int cp = idx2 >> 1;
  const int qt = (xcd & 1) + 2*(idx2 & 1);
  const int c0 = cp*2, r0 = qt*14;

  for (int idx = tid; idx < 1280; idx += 256){
    const int a2 = idx / 320;
    const int ch = a2 & 1, arr = a2 >> 1;
    const int rem = idx % 320;
    const int rr = rem >> 4, cq = rem & 15;
    const int gr = r0 - 3 + rr, gc0 = cq*4 - 4;
    float4 v = {0.f,0.f,0.f,0.f};
    if ((unsigned)gr < 56u){
      const float* src = arr ? (P.x_skip + (size_t)(b*128 + c0 + ch)*HW + gr*56)
                             : (W + OFF_FV + (size_t)(b*128 + c0 + ch)*HW + gr*56);
      if (gc0 >= 0 && gc0 + 3 < 56){
        v = *(const float4*)(src + gc0);
      } else {
        float t[4];
        #pragma unroll
        for (int e=0;e<4;++e){
          const int gc = gc0 + e;
          t[e] = ((unsigned)gc < 56u) ? src[gc] : 0.f;
        }
        v.x=t[0]; v.y=t[1]; v.z=t[2]; v.w=t[3];
      }
    }
    if (arr) *(float4*)&xss[ch][rr][cq*4] = v;
    else     *(float4*)&fvs[ch][rr][cq*4] = v;
  }
  if (tid < 98) w7s[tid/49][tid%49] = W[OFF_W7 + (c0 + tid/49)*49 + tid%49];
  __syncthreads();

  const bool act = tid < 196;
  const int row = tid / 14, q = tid % 14;
  const int q4 = q*4;
  const int grow = r0 + row;
  float acc[2][4];
  {
    const float b0 = W[OFF_BIAS + c0], b1 = W[OFF_BIAS + c0 + 1];
    #pragma unroll
    for (int e=0;e<4;++e){ acc[0][e] = b0; acc[1][e] = b1; }
  }
  if (act){
    const float* dynb = W + OFF_DYN + (size_t)b*49*HW + grow*56 + q4;
    #pragma unroll
    for (int i=0;i<7;++i){
      float4 dr[7];
      #pragma unroll
      for (int j=0;j<7;++j)
        dr[j] = *(const float4*)(dynb + (size_t)(i*7+j)*HW);
      #pragma unroll
      for (int ch=0;ch<2;++ch){
        float fw[12], xw[12];
        {
          float4 t;
          t = *(const float4*)&fvs[ch][row+i][q4];    fw[0]=t.x;fw[1]=t.y;fw[2]=t.z;fw[3]=t.w;
          t = *(const float4*)&fvs[ch][row+i][q4+4];  fw[4]=t.x;fw[5]=t.y;fw[6]=t.z;fw[7]=t.w;
          t = *(const float4*)&fvs[ch][row+i][q4+8];  fw[8]=t.x;fw[9]=t.y;fw[10]=t.z;fw[11]=t.w;
          t = *(const float4*)&xss[ch][row+i][q4];    xw[0]=t.x;xw[1]=t.y;xw[2]=t.z;xw[3]=t.w;
          t = *(const float4*)&xss[ch][row+i][q4+4];  xw[4]=t.x;xw[5]=t.y;xw[6]=t.z;xw[7]=t.w;
          t = *(const float4*)&xss[ch][row+i][q4+8];  xw[8]=t.x;xw[9]=t.y;xw[10]=t.z;xw[11]=t.w;
        }
        #pragma unroll
        for (int j=0;j<7;++j){
          const float4 dv = dr[j];
          const float wv = w7s[ch][i*7+j];
          acc[ch][0] += dv.x*fw[j+1] + wv*xw[j+1];
          acc[ch][1] += dv.y*fw[j+2] + wv*xw[j+2];
          acc[ch][2] += dv.z*fw[j+3] + wv*xw[j+3];
          acc[ch][3] += dv.w*fw[j+4] + wv*xw[j+4];
        }
      }
    }
    #pragma unroll
    for (int ch=0;ch<2;++ch){
      float4 v = {acc[ch][0], acc[ch][1], acc[ch][2], acc[ch][3]};
      *(float4*)(W + OFF_XF + (size_t)(b*128 + c0 + ch)*HW + grow*56 + q4) = v;
    }
  }
  #pragma unroll
  for (int ch=0;ch<2;++ch){
    float s = act ? (acc[ch][0]+acc[ch][1]+acc[ch][2]+acc[ch][3]) : 0.f;
    float mm = act ? fmaxf(fmaxf(acc[ch][0],acc[ch][1]),
                           fmaxf(acc[ch][2],acc[ch][3])) : -1e30f;
    #pragma unroll
    for (int d=1; d<64; d<<=1){
      s += __shfl_xor(s, d, 64);
      mm = fmaxf(mm, __shfl_xor(mm, d, 64));
    }
    if ((tid & 63) == 0){
      atomicAdd(W + OFF_AVG + b*128 + c0 + ch, s);
      atomicMax((u32*)W + OFF_MAXU + b*128 + c0 + ch, fenc(mm));
    }
  }
}

// ---------------------------------------------------------------------------
// K4 (grid 784): CA MLP + gate-GEMM (register-streamed) + epilogue. 2 barriers.
__global__ __launch_bounds__(256) void k_final(Params P){
  __shared__ float xl[128][20];
  __shared__ float hl[16], cal[128];
  float* W = P.W;
  const int tid = threadIdx.x;
  const int x = blockIdx.x, xcd = x & 7;
  const int b = xcd >> 1;
  const int p0 = ((xcd & 1) + 2*(x >> 3)) * 16;

  for (int idx = tid; idx < 512; idx += 256){
    const int c = idx >> 2, pq = idx & 3;
    *(float4*)&xl[c][pq*4] =
        *(const float4*)(P.x_skip + (size_t)(b*128+c)*HW + p0 + pq*4);
  }
  if (tid < 16){
    const int r = tid & 7, which = tid >> 3;
    float a = 0.f;
    #pragma unroll 8
    for (int c=0;c<128;++c){
      const float v = which ? fdec(((u32*)W + OFF_MAXU)[b*128+c])
                            : W[OFF_AVG + b*128+c] * (1.f/3136.f);
      a += P.ca_w1[r*128+c] * v;
    }
    hl[tid] = fmaxf(a, 0.f);
  }
  __syncthreads();                                   // barrier 1 (xl + hl)
  if (tid < 128){
    float a = 0.f;
    #pragma unroll
    for (int r=0;r<8;++r) a += P.ca_w2[tid*8+r] * (hl[r] + hl[8+r]);
    cal[tid] = 1.f/(1.f + __expf(-a));
  }

  const int oq = tid >> 2, pq = tid & 3;
  const int o0 = oq*2, px = pq*4;
  const float4* __restrict__ wr0 = (const float4*)(P.gate_w + (size_t)o0*128);
  const float4* __restrict__ wr1 = (const float4*)(P.gate_w + (size_t)(o0+1)*128);
  float a0[4] = {0.f,0.f,0.f,0.f}, a1[4] = {0.f,0.f,0.f,0.f};
  #pragma unroll 4
  for (int g=0; g<32; ++g){
    const float4 wa = wr0[g], wb = wr1[g];
    const float wav[4] = {wa.x,wa.y,wa.z,wa.w};
    const float wbv[4] = {wb.x,wb.y,wb.z,wb.w};
    #pragma unroll
    for (int t=0; t<4; ++t){
      const float4 x4 = *(const float4*)&xl[g*4+t][px];
      a0[0] += wav[t]*x4.x; a0[1] += wav[t]*x4.y;
      a0[2] += wav[t]*x4.z; a0[3] += wav[t]*x4.w;
      a1[0] += wbv[t]*x4.x; a1[1] += wbv[t]*x4.y;
      a1[2] += wbv[t]*x4.z; a1[3] += wbv[t]*x4.w;
    }
  }
  __syncthreads();                                   // barrier 2 (cal visible)
  const float s0 = P.gate_s[o0], s1 = P.gate_s[o0+1];
  const float c0 = P.gate_b[o0], c1 = P.gate_b[o0+1];
  const float ca0 = cal[o0], ca1 = cal[o0+1];
  const float res = P.res[0];
  const float4 xf0 = *(const float4*)(W + OFF_XF + (size_t)(b*128+o0  )*HW + p0 + px);
  const float4 xf1 = *(const float4*)(W + OFF_XF + (size_t)(b*128+o0+1)*HW + p0 + px);
  const float4 sk0 = *(const float4*)&xl[o0][px];
  const float4 sk1 = *(const float4*)&xl[o0+1][px];
  float g0[4] = {a0[0],a0[1],a0[2],a0[3]};
  float g1[4] = {a1[0],a1[1],a1[2],a1[3]};
  #pragma unroll
  for (int j=0;j<4;++j){
    float y0 = s0*g0[j] + c0, y1 = s1*g1[j] + c1;
    g0[j] = y0 / (1.f + __expf(-y0));
    g1[j] = y1 / (1.f + __expf(-y1));
  }
  float4 o0v, o1v;
  o0v.x = g0[0]*ca0*xf0.x + sk0.x*res;
  o0v.y = g0[1]*ca0*xf0.y + sk0.y*res;
  o0v.z = g0[2]*ca0*xf0.z + sk0.z*res;
  o0v.w = g0[3]*ca0*xf0.w + sk0.w*res;
  o1v.x = g1[0]*ca1*xf1.x + sk1.x*res;
  o1v.y = g1[1]*ca1*xf1.y + sk1.y*res;
  o1v.z = g1[2]*ca1*xf1.z + sk1.z*res;
  o1v.w = g1[3]*ca1*xf1.w + sk1.w*res;
  *(float4*)(P.out + (size_t)(b*128+o0  )*HW + p0 + px) = o0v;
  *(float4*)(P.out + (size_t)(b*128+o0+1)*HW + p0 + px) = o1v;
}

// ---------------------------------------------------------------------------
extern "C" void kernel_launch(void* const* d_in, const int* in_sizes, int n_in,
                              void* d_out, int out_size, void* d_ws, size_t ws_size,
                              hipStream_t stream){
  Params P;
  const float* const* in = (const float* const*)d_in;
  P.x_up = in[0];  P.x_skip = in[1]; P.wq = in[2];  P.bq = in[3];
  P.wk = in[4];    P.bk = in[5];     P.wv = in[6];  P.bv = in[7];
  P.ww = in[8];    P.bw = in[9];
  P.lk_w = in[10]; P.lk_s = in[11];  P.lk_b = in[12];
  P.dw5 = in[13];  P.s5 = in[14];    P.b5 = in[15];
  P.dw3a = in[16]; P.s3a = in[17];   P.b3a = in[18];
  P.dw3b = in[19]; P.s3b = in[20];   P.b3b = in[21];
  P.dw3c = in[22]; P.s3c = in[23];   P.b3c = in[24];
  P.lepe_s = in[25]; P.lepe_b = in[26];
  P.gate_w = in[27]; P.gate_s = in[28]; P.gate_b = in[29];
  P.fus_w = in[30];  P.fus_b = in[31];
  P.ca_w1 = in[32];  P.ca_w2 = in[33]; P.res = in[34];
  P.W = (float*)d_ws;
  P.out = (float*)d_out;

  hipLaunchKernelGGL(k_prep,   dim3(642), dim3(256), 0, stream, P);
  hipLaunchKernelGGL(k_mt,     dim3(196), dim3(256), 0, stream, P);
  hipLaunchKernelGGL(k_qvattn, dim3(784), dim3(256), 0, stream, P);
  hipLaunchKernelGGL(k_mix,    dim3(1024),dim3(256), 0, stream, P);
  hipLaunchKernelGGL(k_final,  dim3(784), dim3(256), 0, stream, P);
}